// Round 9
// baseline (439.530 us; speedup 1.0000x reference)
//
#include <hip/hip_runtime.h>

#define N_TOK 16384
#define HD 1024
#define ID 1024
#define NE 16
#define CAP 2560
#define NKA 32768   // N_TOK * K assignments
#define SEG 8192    // NKA / 4 bucket segments

typedef _Float16 f16;
typedef _Float16 f16x4 __attribute__((ext_vector_type(4)));
typedef _Float16 f16x8 __attribute__((ext_vector_type(8)));
typedef float f32x4 __attribute__((ext_vector_type(4)));

__device__ __forceinline__ void async16(f16* lds, const f16* g) {
  __builtin_amdgcn_global_load_lds(
      (const __attribute__((address_space(1))) unsigned int*)g,
      (__attribute__((address_space(3))) unsigned int*)lds, 16, 0, 0);
}

// ---------------- gate (blocks 0..1023, 4 tokens/wave) + wg/wu cvt (blocks 1024..3071) ----------------
__global__ void gate_kernel(const float* __restrict__ x, const float* __restrict__ gw,
                            int* __restrict__ tokE, float* __restrict__ tokW,
                            f16* __restrict__ Xh,
                            const float* __restrict__ wg, const float* __restrict__ wu,
                            f16* __restrict__ WGh, f16* __restrict__ WUh) {
  if (blockIdx.x >= 1024) {
    int start = ((int)blockIdx.x - 1024) * 256 + (int)threadIdx.x;
    const int stride = 2048 * 256;
    const int n4 = NE * ID * HD / 4;
    for (int i = start; i < n4; i += stride) {
      float4 v = ((const float4*)wg)[i];
      f16x4 h = {(f16)v.x, (f16)v.y, (f16)v.z, (f16)v.w};
      ((f16x4*)WGh)[i] = h;
    }
    for (int i = start; i < n4; i += stride) {
      float4 v = ((const float4*)wu)[i];
      f16x4 h = {(f16)v.x, (f16)v.y, (f16)v.z, (f16)v.w};
      ((f16x4*)WUh)[i] = h;
    }
    return;
  }
  // 4 waves/block, 4 tokens/wave -> 16 tokens/block; gw read once per j per wave (amortized 4x)
  int wv = threadIdx.x >> 6;
  int lane = threadIdx.x & 63;
  int t0 = blockIdx.x * 16 + wv * 4;
  const float4* gr = (const float4*)gw;
  float acc[4][NE];
#pragma unroll
  for (int k = 0; k < 4; k++)
#pragma unroll
    for (int e = 0; e < NE; e++) acc[k][e] = 0.f;
  for (int j = lane; j < HD / 4; j += 64) {
    float4 xv[4];
#pragma unroll
    for (int k = 0; k < 4; k++) {
      xv[k] = ((const float4*)(x + (size_t)(t0 + k) * HD))[j];
      f16x4 h = {(f16)xv[k].x, (f16)xv[k].y, (f16)xv[k].z, (f16)xv[k].w};
      ((f16x4*)(Xh + (size_t)(t0 + k) * HD))[j] = h;
    }
#pragma unroll
    for (int e = 0; e < NE; e++) {
      float4 gv = gr[e * (HD / 4) + j];
#pragma unroll
      for (int k = 0; k < 4; k++)
        acc[k][e] += xv[k].x * gv.x + xv[k].y * gv.y + xv[k].z * gv.z + xv[k].w * gv.w;
    }
  }
#pragma unroll
  for (int k = 0; k < 4; k++)
#pragma unroll
    for (int e = 0; e < NE; e++) {
#pragma unroll
      for (int off = 32; off > 0; off >>= 1) acc[k][e] += __shfl_xor(acc[k][e], off);
    }
  if (lane == 0) {
#pragma unroll
    for (int k = 0; k < 4; k++) {
      int t = t0 + k;
      int i0 = 0;
#pragma unroll
      for (int e = 1; e < NE; e++) if (acc[k][e] > acc[k][i0]) i0 = e;
      int i1 = (i0 == 0) ? 1 : 0;
#pragma unroll
      for (int e = 0; e < NE; e++) if (e != i0 && acc[k][e] > acc[k][i1]) i1 = e;
      float mx = fmaxf(acc[k][i0], acc[k][i1]);
      float p0 = __expf(acc[k][i0] - mx), p1 = __expf(acc[k][i1] - mx);
      float inv = 1.f / (p0 + p1);
      tokE[t * 2] = i0;
      tokE[t * 2 + 1] = i1;
      tokW[t * 2] = p0 * inv;
      tokW[t * 2 + 1] = p1 * inv;
    }
  }
}

// ---------------- bucket: ballot-compaction, 64 blocks = (expert, quarter-segment) ----------------
__global__ __launch_bounds__(1024) void bucket_kernel(
    const int* __restrict__ tokE, const float* __restrict__ tokW,
    int* __restrict__ cntq, int* __restrict__ bTok, float* __restrict__ bW,
    int* __restrict__ bFlat) {
  int e = blockIdx.x >> 2, q = blockIdx.x & 3;
  int tid = threadIdx.x;  // 1024 = 16 waves
  int wid = tid >> 6, lane = tid & 63;
  __shared__ int wsum[16];
  __shared__ int wbase[16];
  __shared__ int chunkTotal;
  int base = q * SEG;
  int total = 0;
  for (int c = 0; c < SEG; c += 1024) {
    int a = base + c + tid;
    bool pred = (tokE[a] == e);
    unsigned long long mask = __ballot(pred);
    int myrank = __popcll(mask & ((1ull << lane) - 1ull));
    if (lane == 0) wsum[wid] = __popcll(mask);
    __syncthreads();
    if (tid == 0) {
      int s = 0;
#pragma unroll
      for (int w = 0; w < 16; w++) { wbase[w] = s; s += wsum[w]; }
      chunkTotal = s;
    }
    __syncthreads();
    if (pred) {
      int pos = base + total + wbase[wid] + myrank;  // compacted within this segment
      bTok[e * NKA + pos] = a >> 1;
      bW[e * NKA + pos] = tokW[a];
      bFlat[e * NKA + pos] = a;
    }
    total += chunkTotal;
    __syncthreads();
  }
  if (tid == 0) cntq[e * 4 + q] = total;
}

// ---------------- rank: capacity selection over 4 gapped segments (order = flat asc) ----------------
__global__ void rank_kernel(const int* __restrict__ cntq, int* __restrict__ mrows,
                            const int* __restrict__ bTok, const float* __restrict__ bW,
                            const int* __restrict__ bFlat, int* __restrict__ rowTok,
                            int* __restrict__ tokSlot) {
  int e = blockIdx.x, tid = threadIdx.x;
  int cq[4], off[4];
  int c = 0;
#pragma unroll
  for (int q = 0; q < 4; q++) { cq[q] = cntq[e * 4 + q]; off[q] = c; c += cq[q]; }
  int m = c < CAP ? c : CAP;
  if (tid == 0) mrows[e] = m;
  if (c <= CAP) {
#pragma unroll
    for (int q = 0; q < 4; q++)
      for (int i = tid; i < cq[q]; i += blockDim.x) {
        int src = e * NKA + q * SEG + i;
        int slot = e * CAP + off[q] + i;
        rowTok[slot] = bTok[src];
        tokSlot[bFlat[src]] = slot;
      }
  } else {
    for (int q = 0; q < 4; q++)
      for (int i = tid; i < cq[q]; i += blockDim.x) {
        int src = e * NKA + q * SEG + i;
        float wp = bW[src];
        int fp = bFlat[src];
        int rank = 0;
        for (int q2 = 0; q2 < 4; q2++)
          for (int j = 0; j < cq[q2]; j++) {
            int s2 = e * NKA + q2 * SEG + j;
            float wq = bW[s2];
            rank += (wq > wp) || (wq == wp && bFlat[s2] < fp);
          }
        if (rank < CAP) {
          int slot = e * CAP + rank;
          rowTok[slot] = bTok[src];
          tokSlot[fp] = slot;
        } else {
          tokSlot[fp] = -1;
        }
      }
  }
}

// ---------------- GEMM1 (blocks 0..5119) + wd cvt tail (blocks 5120..7167) ----------------
// BM=128 x BN=64(g)+64(u) x BK=64; 4 waves 2x2; counted-vmcnt 2-deep pipeline; 64KB LDS -> 2 blocks/CU
__global__ __launch_bounds__(256, 2) void gemm1_kernel(
    const f16* __restrict__ Xh, const f16* __restrict__ WGh, const f16* __restrict__ WUh,
    const int* __restrict__ rowTok, const int* __restrict__ mrows, f16* __restrict__ GU,
    const float* __restrict__ wd, f16* __restrict__ WDh) {
  __shared__ __align__(16) f16 As[2][128 * 64];
  __shared__ __align__(16) f16 Bg[2][64 * 64];
  __shared__ __align__(16) f16 Bu[2][64 * 64];

  if (blockIdx.x >= 5120) {
    // wd fp32->fp16 conversion, hidden in gemm1's tail (gemm2 consumes WDh next launch)
    int start = ((int)blockIdx.x - 5120) * 256 + (int)threadIdx.x;
    const int stride = 2048 * 256;
    const int n4 = NE * HD * ID / 4;
    for (int i = start; i < n4; i += stride) {
      float4 v = ((const float4*)wd)[i];
      f16x4 h = {(f16)v.x, (f16)v.y, (f16)v.z, (f16)v.w};
      ((f16x4*)WDh)[i] = h;
    }
    return;
  }

  int bid = ((int)blockIdx.x & 7) * 640 + ((int)blockIdx.x >> 3);  // XCD swizzle (5120 = 8*640)
  int e = bid / (20 * 16);
  int r2 = bid % (20 * 16);
  int rb = r2 / 16, cb = r2 % 16;
  int me = mrows[e];
  if (rb * 128 >= me) return;

  int tid = threadIdx.x;
  int wave = tid >> 6, lane = tid & 63;
  int wr = wave >> 1, wc = wave & 1;

  // A staging: 128x64 = 4 issues of (256 threads x 16B); gather rows via rowTok, pre-swizzled src
  const f16* aSrc[4];
  int aOff[4];
#pragma unroll
  for (int j = 0; j < 4; j++) {
    int o = j * 256 + tid;
    int row = o >> 3, ch = o & 7;
    int rg = rb * 128 + row;
    int tok = (rg < me) ? rowTok[e * CAP + rg] : 0;
    aSrc[j] = Xh + (size_t)tok * HD + ((ch ^ (row & 7)) * 8);
    aOff[j] = o * 8;
  }
  // B staging: 64x64 = 2 issues each
  const f16* gS[2];
  const f16* uS[2];
  int bOff[2];
#pragma unroll
  for (int j = 0; j < 2; j++) {
    int o = j * 256 + tid;
    int row = o >> 3, ch = o & 7;
    size_t w = (size_t)e * ID * HD + (size_t)(cb * 64 + row) * HD + ((ch ^ (row & 7)) * 8);
    gS[j] = WGh + w;
    uS[j] = WUh + w;
    bOff[j] = o * 8;
  }

  auto stage = [&](int buf, int kt) {
    int kh = kt * 64;
#pragma unroll
    for (int j = 0; j < 4; j++) async16(&As[buf][aOff[j]], aSrc[j] + kh);
#pragma unroll
    for (int j = 0; j < 2; j++) async16(&Bg[buf][bOff[j]], gS[j] + kh);
#pragma unroll
    for (int j = 0; j < 2; j++) async16(&Bu[buf][bOff[j]], uS[j] + kh);
  };

  stage(0, 0);
  stage(1, 1);

  f32x4 accg[4][2] = {};
  f32x4 accu[4][2] = {};

  for (int t = 0; t < 16; t++) {
    int cur = t & 1;
    if (t < 15) asm volatile("s_waitcnt vmcnt(8)" ::: "memory");
    else        asm volatile("s_waitcnt vmcnt(0)" ::: "memory");
    __builtin_amdgcn_s_barrier();
    __builtin_amdgcn_sched_barrier(0);

    f16x8 a[4][2], bg[2][2], bu[2][2];
#pragma unroll
    for (int m = 0; m < 4; m++)
#pragma unroll
      for (int kk = 0; kk < 2; kk++) {
        int row = wr * 64 + m * 16 + (lane & 15);
        int c = (kk * 4 + (lane >> 4)) ^ (row & 7);
        a[m][kk] = *(const f16x8*)&As[cur][row * 64 + c * 8];
      }
#pragma unroll
    for (int n = 0; n < 2; n++)
#pragma unroll
      for (int kk = 0; kk < 2; kk++) {
        int row = wc * 32 + n * 16 + (lane & 15);
        int c = (kk * 4 + (lane >> 4)) ^ (row & 7);
        bg[n][kk] = *(const f16x8*)&Bg[cur][row * 64 + c * 8];
        bu[n][kk] = *(const f16x8*)&Bu[cur][row * 64 + c * 8];
      }
    asm volatile("s_waitcnt lgkmcnt(0)" ::: "memory");
    __builtin_amdgcn_sched_barrier(0);
    __builtin_amdgcn_s_barrier();

    if (t + 2 < 16) stage(cur, t + 2);
    __builtin_amdgcn_sched_barrier(0);  // keep stage issues ahead of MFMA cluster

#pragma unroll
    for (int kk = 0; kk < 2; kk++)
#pragma unroll
      for (int m = 0; m < 4; m++)
#pragma unroll
        for (int n = 0; n < 2; n++) {
          accg[m][n] = __builtin_amdgcn_mfma_f32_16x16x32_f16(a[m][kk], bg[n][kk], accg[m][n], 0, 0, 0);
          accu[m][n] = __builtin_amdgcn_mfma_f32_16x16x32_f16(a[m][kk], bu[n][kk], accu[m][n], 0, 0, 0);
        }
  }

  int rbase = e * CAP + rb * 128 + wr * 64;
  int cbase = cb * 64 + wc * 32;
#pragma unroll
  for (int m = 0; m < 4; m++)
#pragma unroll
    for (int n = 0; n < 2; n++)
#pragma unroll
      for (int r = 0; r < 4; r++) {
        int row = rbase + m * 16 + (lane >> 4) * 4 + r;
        int col = cbase + n * 16 + (lane & 15);
        float g = accg[m][n][r];
        float u = accu[m][n][r];
        float s = g / (1.f + __expf(-g));
        GU[(size_t)row * ID + col] = (f16)(s * u);
      }
}

// ---------------- GEMM2: GU @ wd^T -> OE fp16 ----------------
// BM=128 x BN=128 x BK=64; 4 waves 2x2; counted-vmcnt 2-deep pipeline; 64KB LDS -> 2 blocks/CU
__global__ __launch_bounds__(256, 2) void gemm2_kernel(
    const f16* __restrict__ GU, const f16* __restrict__ WDh,
    const int* __restrict__ mrows, f16* __restrict__ OE) {
  __shared__ __align__(16) f16 As[2][128 * 64];
  __shared__ __align__(16) f16 Bs[2][128 * 64];

  int bid = ((int)blockIdx.x & 7) * 320 + ((int)blockIdx.x >> 3);  // XCD swizzle (2560 = 8*320)
  int e = bid / (20 * 8);
  int r2 = bid % (20 * 8);
  int rb = r2 / 8, cb = r2 % 8;
  if (rb * 128 >= mrows[e]) return;

  int tid = threadIdx.x;
  int wave = tid >> 6, lane = tid & 63;
  int wr = wave >> 1, wc = wave & 1;

  const f16* aSrc[4];
  const f16* bSrc[4];
  int sOff[4];
#pragma unroll
  for (int j = 0; j < 4; j++) {
    int o = j * 256 + tid;
    int row = o >> 3, ch = o & 7;
    int sw = (ch ^ (row & 7)) * 8;
    aSrc[j] = GU + (size_t)(e * CAP + rb * 128 + row) * ID + sw;
    bSrc[j] = WDh + (size_t)e * HD * ID + (size_t)(cb * 128 + row) * ID + sw;
    sOff[j] = o * 8;
  }

  auto stage = [&](int buf, int kt) {
    int kh = kt * 64;
#pragma unroll
    for (int j = 0; j < 4; j++) async16(&As[buf][sOff[j]], aSrc[j] + kh);
#pragma unroll
    for (int j = 0; j < 4; j++) async16(&Bs[buf][sOff[j]], bSrc[j] + kh);
  };

  stage(0, 0);
  stage(1, 1);

  f32x4 acc[4][4] = {};

  for (int t = 0; t < 16; t++) {
    int cur = t & 1;
    if (t < 15) asm volatile("s_waitcnt vmcnt(8)" ::: "memory");
    else        asm volatile("s_waitcnt vmcnt(0)" ::: "memory");
    __builtin_amdgcn_s_barrier();
    __builtin_amdgcn_sched_barrier(0);

    f16x8 a[4][2], b[4][2];
#pragma unroll
    for (int m = 0; m < 4; m++)
#pragma unroll
      for (int kk = 0; kk < 2; kk++) {
        int row = wr * 64 + m * 16 + (lane & 15);
        int c = (kk * 4 + (lane >> 4)) ^ (row & 7);
        a[m][kk] = *(const f16x8*)&As[cur][row * 64 + c * 8];
      }
#pragma unroll
    for (int n = 0; n < 4; n++)
#pragma unroll
      for (int kk = 0; kk < 2; kk++) {
        int row = wc * 64 + n * 16 + (lane & 15);
        int c = (kk * 4 + (lane >> 4)) ^ (row & 7);
        b[n][kk] = *(const f16x8*)&Bs[cur][row * 64 + c * 8];
      }
    asm volatile("s_waitcnt lgkmcnt(0)" ::: "memory");
    __builtin_amdgcn_sched_barrier(0);
    __builtin_amdgcn_s_barrier();

    if (t + 2 < 16) stage(cur, t + 2);
    __builtin_amdgcn_sched_barrier(0);

#pragma unroll
    for (int kk = 0; kk < 2; kk++)
#pragma unroll
      for (int m = 0; m < 4; m++)
#pragma unroll
        for (int n = 0; n < 4; n++)
          acc[m][n] = __builtin_amdgcn_mfma_f32_16x16x32_f16(a[m][kk], b[n][kk], acc[m][n], 0, 0, 0);
  }

  int rbase = e * CAP + rb * 128 + wr * 64;
  int cbase = cb * 128 + wc * 64;
#pragma unroll
  for (int m = 0; m < 4; m++)
#pragma unroll
    for (int n = 0; n < 4; n++)
#pragma unroll
      for (int r = 0; r < 4; r++) {
        int row = rbase + m * 16 + (lane >> 4) * 4 + r;
        int col = cbase + n * 16 + (lane & 15);
        OE[(size_t)row * HD + col] = (f16)acc[m][n][r];
      }
}

// ---------------- combine: out[t] = sum_k w_k * OE[slot_k] (128 thr, 8 cols each) ----------------
__global__ void combine_kernel(const f16* __restrict__ OE, const int* __restrict__ tokSlot,
                               const float* __restrict__ tokW, float* __restrict__ out) {
  int t = blockIdx.x, tid = threadIdx.x;
  int s0 = tokSlot[t * 2], s1 = tokSlot[t * 2 + 1];
  float w0 = tokW[t * 2], w1 = tokW[t * 2 + 1];
  int c = tid * 8;
  float o[8] = {};
  if (s0 >= 0) {
    f16x8 v = *(const f16x8*)&OE[(size_t)s0 * HD + c];
#pragma unroll
    for (int j = 0; j < 8; j++) o[j] += w0 * (float)v[j];
  }
  if (s1 >= 0) {
    f16x8 v = *(const f16x8*)&OE[(size_t)s1 * HD + c];
#pragma unroll
    for (int j = 0; j < 8; j++) o[j] += w1 * (float)v[j];
  }
  float4 lo = {o[0], o[1], o[2], o[3]}, hi = {o[4], o[5], o[6], o[7]};
  *(float4*)&out[(size_t)t * HD + c] = lo;
  *(float4*)&out[(size_t)t * HD + c + 4] = hi;
  if (t == 0 && tid == 0) out[(size_t)N_TOK * HD] = 0.f;  // aux_loss
}

extern "C" void kernel_launch(void* const* d_in, const int* in_sizes, int n_in,
                              void* d_out, int out_size, void* d_ws, size_t ws_size,
                              hipStream_t stream) {
  (void)in_sizes; (void)n_in; (void)out_size; (void)ws_size;
  const float* x  = (const float*)d_in[0];
  const float* gw = (const float*)d_in[1];
  const float* wg = (const float*)d_in[2];
  const float* wu = (const float*)d_in[3];
  const float* wd = (const float*)d_in[4];
  float* out = (float*)d_out;

  char* ws = (char*)d_ws;
  f16* Xh  = (f16*)ws;                          // 32 MB
  f16* WGh = (f16*)(ws + 33554432ll);           // 32 MB
  f16* WUh = (f16*)(ws + 67108864ll);           // 32 MB
  f16* WDh = (f16*)(ws + 100663296ll);          // 32 MB
  f16* GU  = (f16*)(ws + 134217728ll);          // 80 MB
  f16* OE  = (f16*)ws;                          // aliases Xh/WGh (dead by GEMM2)
  char* rt = ws + 218103808ll;
  int*   cntq    = (int*)rt;                    // 256 B (16 experts x 4 segments)
  int*   mrows   = (int*)(rt + 256);            // 64 B
  int*   rowTok  = (int*)(rt + 512);            // 160 KB
  int*   tokSlot = (int*)(rt + 512 + 163840);   // 128 KB
  float* tokW    = (float*)(rt + 512 + 163840 + 131072);
  char*  rb      = rt + 512 + 163840 + 131072 + 131072;
  int*   bTok  = (int*)rb;                      // 2 MB
  float* bW    = (float*)(rb + 2097152);        // 2 MB
  int*   bFlat = (int*)(rb + 4194304);          // 2 MB
  int*   tokE  = (int*)(rb + 6291456);          // 128 KB

  gate_kernel<<<1024 + 2048, 256, 0, stream>>>(x, gw, tokE, tokW, Xh, wg, wu, WGh, WUh);
  bucket_kernel<<<64, 1024, 0, stream>>>(tokE, tokW, cntq, bTok, bW, bFlat);
  rank_kernel<<<NE, 256, 0, stream>>>(cntq, mrows, bTok, bW, bFlat, rowTok, tokSlot);
  gemm1_kernel<<<5120 + 2048, 256, 0, stream>>>(Xh, WGh, WUh, rowTok, mrows, GU, wd, WDh);
  gemm2_kernel<<<NE * 20 * 8, 256, 0, stream>>>(GU, WDh, mrows, OE);
  combine_kernel<<<N_TOK, 128, 0, stream>>>(OE, tokSlot, tokW, out);
}

// Round 10
// 408.313 us; speedup vs baseline: 1.0765x; 1.0765x over previous
//
#include <hip/hip_runtime.h>

#define N_TOK 16384
#define HD 1024
#define ID 1024
#define NE 16
#define CAP 2560
#define NKA 32768   // N_TOK * K assignments
#define SEG 8192    // NKA / 4 bucket segments

typedef _Float16 f16;
typedef _Float16 f16x4 __attribute__((ext_vector_type(4)));
typedef _Float16 f16x8 __attribute__((ext_vector_type(8)));
typedef float f32x4 __attribute__((ext_vector_type(4)));

__device__ __forceinline__ void async16(f16* lds, const f16* g) {
  __builtin_amdgcn_global_load_lds(
      (const __attribute__((address_space(1))) unsigned int*)g,
      (__attribute__((address_space(3))) unsigned int*)lds, 16, 0, 0);
}

// ---------------- gate (blocks 0..4095) + wg/wu fp32->fp16 cvt (blocks 4096..6143) ----------------
__global__ void gate_kernel(const float* __restrict__ x, const float* __restrict__ gw,
                            int* __restrict__ tokE, float* __restrict__ tokW,
                            f16* __restrict__ Xh,
                            const float* __restrict__ wg, const float* __restrict__ wu,
                            f16* __restrict__ WGh, f16* __restrict__ WUh) {
  if (blockIdx.x >= 4096) {
    int start = ((int)blockIdx.x - 4096) * 256 + (int)threadIdx.x;
    const int stride = 2048 * 256;
    const int n4 = NE * ID * HD / 4;
    for (int i = start; i < n4; i += stride) {
      float4 v = ((const float4*)wg)[i];
      f16x4 h = {(f16)v.x, (f16)v.y, (f16)v.z, (f16)v.w};
      ((f16x4*)WGh)[i] = h;
    }
    for (int i = start; i < n4; i += stride) {
      float4 v = ((const float4*)wu)[i];
      f16x4 h = {(f16)v.x, (f16)v.y, (f16)v.z, (f16)v.w};
      ((f16x4*)WUh)[i] = h;
    }
    return;
  }
  int t = blockIdx.x * 4 + (threadIdx.x >> 6);
  int lane = threadIdx.x & 63;
  const float4* xr = (const float4*)(x + (size_t)t * HD);
  const float4* gr = (const float4*)gw;
  f16x4* xw = (f16x4*)(Xh + (size_t)t * HD);
  float acc[NE];
#pragma unroll
  for (int e = 0; e < NE; e++) acc[e] = 0.f;
  for (int j = lane; j < HD / 4; j += 64) {
    float4 xv = xr[j];
    f16x4 h = {(f16)xv.x, (f16)xv.y, (f16)xv.z, (f16)xv.w};
    xw[j] = h;
#pragma unroll
    for (int e = 0; e < NE; e++) {
      float4 gv = gr[e * (HD / 4) + j];
      acc[e] += xv.x * gv.x + xv.y * gv.y + xv.z * gv.z + xv.w * gv.w;
    }
  }
#pragma unroll
  for (int e = 0; e < NE; e++) {
#pragma unroll
    for (int off = 32; off > 0; off >>= 1) acc[e] += __shfl_xor(acc[e], off);
  }
  if (lane == 0) {
    int i0 = 0;
#pragma unroll
    for (int e = 1; e < NE; e++) if (acc[e] > acc[i0]) i0 = e;
    int i1 = (i0 == 0) ? 1 : 0;
#pragma unroll
    for (int e = 0; e < NE; e++) if (e != i0 && acc[e] > acc[i1]) i1 = e;
    float mx = fmaxf(acc[i0], acc[i1]);
    float p0 = __expf(acc[i0] - mx), p1 = __expf(acc[i1] - mx);
    float inv = 1.f / (p0 + p1);
    tokE[t * 2] = i0;
    tokE[t * 2 + 1] = i1;
    tokW[t * 2] = p0 * inv;
    tokW[t * 2 + 1] = p1 * inv;
  }
}

// ---------------- bucket: ballot-compaction, 64 blocks = (expert, quarter-segment) ----------------
__global__ __launch_bounds__(1024) void bucket_kernel(
    const int* __restrict__ tokE, const float* __restrict__ tokW,
    int* __restrict__ cntq, int* __restrict__ bTok, float* __restrict__ bW,
    int* __restrict__ bFlat) {
  int e = blockIdx.x >> 2, q = blockIdx.x & 3;
  int tid = threadIdx.x;  // 1024 = 16 waves
  int wid = tid >> 6, lane = tid & 63;
  __shared__ int wsum[16];
  __shared__ int wbase[16];
  __shared__ int chunkTotal;
  int base = q * SEG;
  int total = 0;
  for (int c = 0; c < SEG; c += 1024) {
    int a = base + c + tid;
    bool pred = (tokE[a] == e);
    unsigned long long mask = __ballot(pred);
    int myrank = __popcll(mask & ((1ull << lane) - 1ull));
    if (lane == 0) wsum[wid] = __popcll(mask);
    __syncthreads();
    if (tid == 0) {
      int s = 0;
#pragma unroll
      for (int w = 0; w < 16; w++) { wbase[w] = s; s += wsum[w]; }
      chunkTotal = s;
    }
    __syncthreads();
    if (pred) {
      int pos = base + total + wbase[wid] + myrank;  // compacted within this segment
      bTok[e * NKA + pos] = a >> 1;
      bW[e * NKA + pos] = tokW[a];
      bFlat[e * NKA + pos] = a;
    }
    total += chunkTotal;
    __syncthreads();
  }
  if (tid == 0) cntq[e * 4 + q] = total;
}

// ---------------- rank: capacity selection over 4 gapped segments (order = flat asc) ----------------
__global__ void rank_kernel(const int* __restrict__ cntq, int* __restrict__ mrows,
                            const int* __restrict__ bTok, const float* __restrict__ bW,
                            const int* __restrict__ bFlat, int* __restrict__ rowTok,
                            int* __restrict__ tokSlot) {
  int e = blockIdx.x, tid = threadIdx.x;
  int cq[4], off[4];
  int c = 0;
#pragma unroll
  for (int q = 0; q < 4; q++) { cq[q] = cntq[e * 4 + q]; off[q] = c; c += cq[q]; }
  int m = c < CAP ? c : CAP;
  if (tid == 0) mrows[e] = m;
  if (c <= CAP) {
#pragma unroll
    for (int q = 0; q < 4; q++)
      for (int i = tid; i < cq[q]; i += blockDim.x) {
        int src = e * NKA + q * SEG + i;
        int slot = e * CAP + off[q] + i;
        rowTok[slot] = bTok[src];
        tokSlot[bFlat[src]] = slot;
      }
  } else {
    for (int q = 0; q < 4; q++)
      for (int i = tid; i < cq[q]; i += blockDim.x) {
        int src = e * NKA + q * SEG + i;
        float wp = bW[src];
        int fp = bFlat[src];
        int rank = 0;
        for (int q2 = 0; q2 < 4; q2++)
          for (int j = 0; j < cq[q2]; j++) {
            int s2 = e * NKA + q2 * SEG + j;
            float wq = bW[s2];
            rank += (wq > wp) || (wq == wp && bFlat[s2] < fp);
          }
        if (rank < CAP) {
          int slot = e * CAP + rank;
          rowTok[slot] = bTok[src];
          tokSlot[fp] = slot;
        } else {
          tokSlot[fp] = -1;
        }
      }
  }
}

// ---------------- GEMM1 (blocks 0..5119) + wd cvt tail (blocks 5120..7167) ----------------
// BM=128 x BN=64(g)+64(u) x BK=64; 4 waves 2x2; counted-vmcnt 2-deep pipeline; 64KB LDS -> 2 blocks/CU
__global__ __launch_bounds__(256, 2) void gemm1_kernel(
    const f16* __restrict__ Xh, const f16* __restrict__ WGh, const f16* __restrict__ WUh,
    const int* __restrict__ rowTok, const int* __restrict__ mrows, f16* __restrict__ GU,
    const float* __restrict__ wd, f16* __restrict__ WDh) {
  __shared__ __align__(16) f16 As[2][128 * 64];
  __shared__ __align__(16) f16 Bg[2][64 * 64];
  __shared__ __align__(16) f16 Bu[2][64 * 64];

  if (blockIdx.x >= 5120) {
    // wd fp32->fp16 conversion, hidden in gemm1's tail (gemm2 consumes WDh next launch)
    int start = ((int)blockIdx.x - 5120) * 256 + (int)threadIdx.x;
    const int stride = 2048 * 256;
    const int n4 = NE * HD * ID / 4;
    for (int i = start; i < n4; i += stride) {
      float4 v = ((const float4*)wd)[i];
      f16x4 h = {(f16)v.x, (f16)v.y, (f16)v.z, (f16)v.w};
      ((f16x4*)WDh)[i] = h;
    }
    return;
  }

  int bid = ((int)blockIdx.x & 7) * 640 + ((int)blockIdx.x >> 3);  // XCD swizzle (5120 = 8*640)
  int e = bid / (20 * 16);
  int r2 = bid % (20 * 16);
  int rb = r2 / 16, cb = r2 % 16;
  int me = mrows[e];
  if (rb * 128 >= me) return;

  int tid = threadIdx.x;
  int wave = tid >> 6, lane = tid & 63;
  int wr = wave >> 1, wc = wave & 1;

  // A staging: 128x64 = 4 issues of (256 threads x 16B); gather rows via rowTok, pre-swizzled src
  const f16* aSrc[4];
  int aOff[4];
#pragma unroll
  for (int j = 0; j < 4; j++) {
    int o = j * 256 + tid;
    int row = o >> 3, ch = o & 7;
    int rg = rb * 128 + row;
    int tok = (rg < me) ? rowTok[e * CAP + rg] : 0;
    aSrc[j] = Xh + (size_t)tok * HD + ((ch ^ (row & 7)) * 8);
    aOff[j] = o * 8;
  }
  // B staging: 64x64 = 2 issues each
  const f16* gS[2];
  const f16* uS[2];
  int bOff[2];
#pragma unroll
  for (int j = 0; j < 2; j++) {
    int o = j * 256 + tid;
    int row = o >> 3, ch = o & 7;
    size_t w = (size_t)e * ID * HD + (size_t)(cb * 64 + row) * HD + ((ch ^ (row & 7)) * 8);
    gS[j] = WGh + w;
    uS[j] = WUh + w;
    bOff[j] = o * 8;
  }

  auto stage = [&](int buf, int kt) {
    int kh = kt * 64;
#pragma unroll
    for (int j = 0; j < 4; j++) async16(&As[buf][aOff[j]], aSrc[j] + kh);
#pragma unroll
    for (int j = 0; j < 2; j++) async16(&Bg[buf][bOff[j]], gS[j] + kh);
#pragma unroll
    for (int j = 0; j < 2; j++) async16(&Bu[buf][bOff[j]], uS[j] + kh);
  };

  stage(0, 0);
  stage(1, 1);

  f32x4 accg[4][2] = {};
  f32x4 accu[4][2] = {};

  for (int t = 0; t < 16; t++) {
    int cur = t & 1;
    if (t < 15) asm volatile("s_waitcnt vmcnt(8)" ::: "memory");
    else        asm volatile("s_waitcnt vmcnt(0)" ::: "memory");
    __builtin_amdgcn_s_barrier();
    __builtin_amdgcn_sched_barrier(0);

    f16x8 a[4][2], bg[2][2], bu[2][2];
#pragma unroll
    for (int m = 0; m < 4; m++)
#pragma unroll
      for (int kk = 0; kk < 2; kk++) {
        int row = wr * 64 + m * 16 + (lane & 15);
        int c = (kk * 4 + (lane >> 4)) ^ (row & 7);
        a[m][kk] = *(const f16x8*)&As[cur][row * 64 + c * 8];
      }
#pragma unroll
    for (int n = 0; n < 2; n++)
#pragma unroll
      for (int kk = 0; kk < 2; kk++) {
        int row = wc * 32 + n * 16 + (lane & 15);
        int c = (kk * 4 + (lane >> 4)) ^ (row & 7);
        bg[n][kk] = *(const f16x8*)&Bg[cur][row * 64 + c * 8];
        bu[n][kk] = *(const f16x8*)&Bu[cur][row * 64 + c * 8];
      }
    asm volatile("s_waitcnt lgkmcnt(0)" ::: "memory");
    __builtin_amdgcn_sched_barrier(0);
    __builtin_amdgcn_s_barrier();

    if (t + 2 < 16) stage(cur, t + 2);
    __builtin_amdgcn_sched_barrier(0);  // keep stage issues ahead of MFMA cluster

#pragma unroll
    for (int kk = 0; kk < 2; kk++)
#pragma unroll
      for (int m = 0; m < 4; m++)
#pragma unroll
        for (int n = 0; n < 2; n++) {
          accg[m][n] = __builtin_amdgcn_mfma_f32_16x16x32_f16(a[m][kk], bg[n][kk], accg[m][n], 0, 0, 0);
          accu[m][n] = __builtin_amdgcn_mfma_f32_16x16x32_f16(a[m][kk], bu[n][kk], accu[m][n], 0, 0, 0);
        }
  }

  int rbase = e * CAP + rb * 128 + wr * 64;
  int cbase = cb * 64 + wc * 32;
#pragma unroll
  for (int m = 0; m < 4; m++)
#pragma unroll
    for (int n = 0; n < 2; n++)
#pragma unroll
      for (int r = 0; r < 4; r++) {
        int row = rbase + m * 16 + (lane >> 4) * 4 + r;
        int col = cbase + n * 16 + (lane & 15);
        float g = accg[m][n][r];
        float u = accu[m][n][r];
        float s = g / (1.f + __expf(-g));
        GU[(size_t)row * ID + col] = (f16)(s * u);
      }
}

// ---------------- GEMM2: GU @ wd^T -> OE fp16 ----------------
// BM=128 x BN=128 x BK=64; 4 waves 2x2; counted-vmcnt 2-deep pipeline; 64KB LDS -> 2 blocks/CU
__global__ __launch_bounds__(256, 2) void gemm2_kernel(
    const f16* __restrict__ GU, const f16* __restrict__ WDh,
    const int* __restrict__ mrows, f16* __restrict__ OE) {
  __shared__ __align__(16) f16 As[2][128 * 64];
  __shared__ __align__(16) f16 Bs[2][128 * 64];

  int bid = ((int)blockIdx.x & 7) * 320 + ((int)blockIdx.x >> 3);  // XCD swizzle (2560 = 8*320)
  int e = bid / (20 * 8);
  int r2 = bid % (20 * 8);
  int rb = r2 / 8, cb = r2 % 8;
  if (rb * 128 >= mrows[e]) return;

  int tid = threadIdx.x;
  int wave = tid >> 6, lane = tid & 63;
  int wr = wave >> 1, wc = wave & 1;

  const f16* aSrc[4];
  const f16* bSrc[4];
  int sOff[4];
#pragma unroll
  for (int j = 0; j < 4; j++) {
    int o = j * 256 + tid;
    int row = o >> 3, ch = o & 7;
    int sw = (ch ^ (row & 7)) * 8;
    aSrc[j] = GU + (size_t)(e * CAP + rb * 128 + row) * ID + sw;
    bSrc[j] = WDh + (size_t)e * HD * ID + (size_t)(cb * 128 + row) * ID + sw;
    sOff[j] = o * 8;
  }

  auto stage = [&](int buf, int kt) {
    int kh = kt * 64;
#pragma unroll
    for (int j = 0; j < 4; j++) async16(&As[buf][sOff[j]], aSrc[j] + kh);
#pragma unroll
    for (int j = 0; j < 4; j++) async16(&Bs[buf][sOff[j]], bSrc[j] + kh);
  };

  stage(0, 0);
  stage(1, 1);

  f32x4 acc[4][4] = {};

  for (int t = 0; t < 16; t++) {
    int cur = t & 1;
    if (t < 15) asm volatile("s_waitcnt vmcnt(8)" ::: "memory");
    else        asm volatile("s_waitcnt vmcnt(0)" ::: "memory");
    __builtin_amdgcn_s_barrier();
    __builtin_amdgcn_sched_barrier(0);

    f16x8 a[4][2], b[4][2];
#pragma unroll
    for (int m = 0; m < 4; m++)
#pragma unroll
      for (int kk = 0; kk < 2; kk++) {
        int row = wr * 64 + m * 16 + (lane & 15);
        int c = (kk * 4 + (lane >> 4)) ^ (row & 7);
        a[m][kk] = *(const f16x8*)&As[cur][row * 64 + c * 8];
      }
#pragma unroll
    for (int n = 0; n < 4; n++)
#pragma unroll
      for (int kk = 0; kk < 2; kk++) {
        int row = wc * 64 + n * 16 + (lane & 15);
        int c = (kk * 4 + (lane >> 4)) ^ (row & 7);
        b[n][kk] = *(const f16x8*)&Bs[cur][row * 64 + c * 8];
      }
    asm volatile("s_waitcnt lgkmcnt(0)" ::: "memory");
    __builtin_amdgcn_sched_barrier(0);
    __builtin_amdgcn_s_barrier();

    if (t + 2 < 16) stage(cur, t + 2);
    __builtin_amdgcn_sched_barrier(0);

#pragma unroll
    for (int kk = 0; kk < 2; kk++)
#pragma unroll
      for (int m = 0; m < 4; m++)
#pragma unroll
        for (int n = 0; n < 4; n++)
          acc[m][n] = __builtin_amdgcn_mfma_f32_16x16x32_f16(a[m][kk], b[n][kk], acc[m][n], 0, 0, 0);
  }

  int rbase = e * CAP + rb * 128 + wr * 64;
  int cbase = cb * 128 + wc * 64;
#pragma unroll
  for (int m = 0; m < 4; m++)
#pragma unroll
    for (int n = 0; n < 4; n++)
#pragma unroll
      for (int r = 0; r < 4; r++) {
        int row = rbase + m * 16 + (lane >> 4) * 4 + r;
        int col = cbase + n * 16 + (lane & 15);
        OE[(size_t)row * HD + col] = (f16)acc[m][n][r];
      }
}

// ---------------- combine: out[t] = sum_k w_k * OE[slot_k] (128 thr, 8 cols each) ----------------
__global__ void combine_kernel(const f16* __restrict__ OE, const int* __restrict__ tokSlot,
                               const float* __restrict__ tokW, float* __restrict__ out) {
  int t = blockIdx.x, tid = threadIdx.x;
  int s0 = tokSlot[t * 2], s1 = tokSlot[t * 2 + 1];
  float w0 = tokW[t * 2], w1 = tokW[t * 2 + 1];
  int c = tid * 8;
  float o[8] = {};
  if (s0 >= 0) {
    f16x8 v = *(const f16x8*)&OE[(size_t)s0 * HD + c];
#pragma unroll
    for (int j = 0; j < 8; j++) o[j] += w0 * (float)v[j];
  }
  if (s1 >= 0) {
    f16x8 v = *(const f16x8*)&OE[(size_t)s1 * HD + c];
#pragma unroll
    for (int j = 0; j < 8; j++) o[j] += w1 * (float)v[j];
  }
  float4 lo = {o[0], o[1], o[2], o[3]}, hi = {o[4], o[5], o[6], o[7]};
  *(float4*)&out[(size_t)t * HD + c] = lo;
  *(float4*)&out[(size_t)t * HD + c + 4] = hi;
  if (t == 0 && tid == 0) out[(size_t)N_TOK * HD] = 0.f;  // aux_loss
}

extern "C" void kernel_launch(void* const* d_in, const int* in_sizes, int n_in,
                              void* d_out, int out_size, void* d_ws, size_t ws_size,
                              hipStream_t stream) {
  (void)in_sizes; (void)n_in; (void)out_size; (void)ws_size;
  const float* x  = (const float*)d_in[0];
  const float* gw = (const float*)d_in[1];
  const float* wg = (const float*)d_in[2];
  const float* wu = (const float*)d_in[3];
  const float* wd = (const float*)d_in[4];
  float* out = (float*)d_out;

  char* ws = (char*)d_ws;
  f16* Xh  = (f16*)ws;                          // 32 MB
  f16* WGh = (f16*)(ws + 33554432ll);           // 32 MB
  f16* WUh = (f16*)(ws + 67108864ll);           // 32 MB
  f16* WDh = (f16*)(ws + 100663296ll);          // 32 MB
  f16* GU  = (f16*)(ws + 134217728ll);          // 80 MB
  f16* OE  = (f16*)ws;                          // aliases Xh/WGh (dead by GEMM2)
  char* rt = ws + 218103808ll;
  int*   cntq    = (int*)rt;                    // 256 B (16 experts x 4 segments)
  int*   mrows   = (int*)(rt + 256);            // 64 B
  int*   rowTok  = (int*)(rt + 512);            // 160 KB
  int*   tokSlot = (int*)(rt + 512 + 163840);   // 128 KB
  float* tokW    = (float*)(rt + 512 + 163840 + 131072);
  char*  rb      = rt + 512 + 163840 + 131072 + 131072;
  int*   bTok  = (int*)rb;                      // 2 MB
  float* bW    = (float*)(rb + 2097152);        // 2 MB
  int*   bFlat = (int*)(rb + 4194304);          // 2 MB
  int*   tokE  = (int*)(rb + 6291456);          // 128 KB

  gate_kernel<<<4096 + 2048, 256, 0, stream>>>(x, gw, tokE, tokW, Xh, wg, wu, WGh, WUh);
  bucket_kernel<<<64, 1024, 0, stream>>>(tokE, tokW, cntq, bTok, bW, bFlat);
  rank_kernel<<<NE, 256, 0, stream>>>(cntq, mrows, bTok, bW, bFlat, rowTok, tokSlot);
  gemm1_kernel<<<5120 + 2048, 256, 0, stream>>>(Xh, WGh, WUh, rowTok, mrows, GU, wd, WDh);
  gemm2_kernel<<<NE * 20 * 8, 256, 0, stream>>>(GU, WDh, mrows, OE);
  combine_kernel<<<N_TOK, 128, 0, stream>>>(OE, tokSlot, tokW, out);
}